// Round 8
// baseline (432.335 us; speedup 1.0000x reference)
//
#include <hip/hip_runtime.h>
#include <hip/hip_bf16.h>
#include <math.h>

// SupCon loss, N=8192 D=128 fp32 in, scalar fp32 out.
// Round 11: sim is latency-bound at ~2 waves/SIMD. VGPR_Count=128 excludes
// accumulators (gfx950 unified file): true per-wave usage ~192 regs ->
// 2048/192 = 10 waves/CU. Fix: 512-thread blocks, 8 waves, wave tile 32x64
// (was 64x64): Af 64->32, acc 64->32, RE/RP 32->16, li 16->8, total ~123 regs,
// __launch_bounds__(512,4) enforces <=128 -> 16 waves/CU = 4 waves/SIMD (2x
// concurrency). Same MFMA count, same B-load count, same partial-store slots.
// Pipeline otherwise = R10: zero -> prep(fragment-major Fb + hist) ->
// sim (no LDS, no barriers, no atomics) -> reduce (128 blocks).

constexpr int N = 8192;
constexpr int D = 128;

typedef __attribute__((ext_vector_type(8))) short short8;  // 8 bf16 = 4 VGPRs
typedef __attribute__((ext_vector_type(4))) float f32x4;

constexpr float SELF_POISON = -50.0f;  // exp2(-50) ~ 9e-16; |s2| <= 14.43 real

__device__ __forceinline__ float fast_exp2(float x) {
#if __has_builtin(__builtin_amdgcn_exp2f)
    return __builtin_amdgcn_exp2f(x);
#else
    return __expf(x * 0.69314718056f);
#endif
}

// ---------------- zero: hist + output accumulator ---------------------------
__global__ void zero_kernel(int* __restrict__ hist, float* __restrict__ out) {
    hist[threadIdx.x] = 0;  // <<<1,1024>>>
    if (threadIdx.x == 0) out[0] = 0.0f;
}

// ---------------- prep: bf16 rows scaled into log2 domain, fragment layout --
// FbP uint index for element pair (row, k=2l): (row>>4)*1024 + (l>>2)*64 +
// (row&15)*4 + (l&3). Chunk chi = l>>2 holds k = 8*chi .. 8*chi+7 in order.
__global__ void prep_kernel(const float* __restrict__ F,
                            const int* __restrict__ labels,
                            unsigned int* __restrict__ FbP,
                            int* __restrict__ hist) {
    int row = blockIdx.x * 4 + (threadIdx.x >> 6);
    int l = threadIdx.x & 63;
    float2 v = ((const float2*)(F + (size_t)row * D))[l];
    float ss = v.x * v.x + v.y * v.y;
#pragma unroll
    for (int off = 32; off > 0; off >>= 1) ss += __shfl_xor(ss, off);
    float sc = sqrtf(14.4269504089f / ss);  // 10 * log2(e), folded
    __hip_bfloat16 hx = __float2bfloat16(v.x * sc);
    __hip_bfloat16 hy = __float2bfloat16(v.y * sc);
    unsigned int ux = *(unsigned short*)&hx;
    unsigned int uy = *(unsigned short*)&hy;
    unsigned int idx = ((unsigned)(row >> 4) << 10) | ((unsigned)(l >> 2) << 6) |
                       ((unsigned)(row & 15) << 2) | (unsigned)(l & 3);
    FbP[idx] = ux | (uy << 16);
    if (l == 0) atomicAdd(&hist[labels[row]], 1);
}

// ---------------- sim: full matrix, MFMA, no LDS/barriers/atomics -----------
// Block (ti,g): 128x128 rows x [4g,4g+3] col-tiles. 512 threads = 8 waves;
// wave (wy,wx) owns rows wy*32..+32, cols wx*64..+64 of each 128x128 tile.
__global__ __launch_bounds__(512, 4) void sim_kernel(
    const short8* __restrict__ P, const int* __restrict__ labels,
    float* __restrict__ partE, float* __restrict__ partP) {
    const int ti = blockIdx.x >> 4;   // 64 row tiles
    const int g  = blockIdx.x & 15;   // 16 column groups
    const int tjs = g * 4;
    const int i0 = ti * 128;

    const int t = threadIdx.x, w = t >> 6, l = t & 63;
    const int c = l & 15, quad = l >> 4;    // MFMA lane split
    const int wy = w >> 2, wx = w & 3;      // hmm -- see below; fixed next line
    // 8 waves: 4 row-groups x 2 col-halves
    const int ry = w >> 1;                  // 0..3: rows ry*32..+32
    const int cx = w & 1;                   // 0..1: cols cx*64..+64
    (void)wy; (void)wx;

    // A fragments for the strip: 8 x 1KB coalesced loads, 32 VGPR.
    short8 Af[4][2];  // [kk][m], row16 = ry*2 + m
#pragma unroll
    for (int kk = 0; kk < 4; ++kk)
#pragma unroll
        for (int m = 0; m < 2; ++m)
            Af[kk][m] = P[(ti * 8 + ry * 2 + m) * 256 + kk * 64 + l];

    // row labels for this wave's rows (strip-constant)
    int li[2][4];
#pragma unroll
    for (int m = 0; m < 2; ++m)
#pragma unroll
        for (int r = 0; r < 4; ++r)
            li[m][r] = labels[i0 + ry * 32 + m * 16 + quad * 4 + r];

    const bool selfQuad = (quad == (c >> 2));  // lane may hold self elements
    const bool diagWave = (cx == (ry >> 1));   // wave's cols contain its rows

    float RE[2][4] = {}, RP[2][4] = {};  // row partials, carried across strip

#pragma unroll 1
    for (int tj = tjs; tj < tjs + 4; ++tj) {
        const int j0 = tj * 128;
        int lj[4];
#pragma unroll
        for (int n = 0; n < 4; ++n) lj[n] = labels[j0 + cx * 64 + n * 16 + c];

        f32x4 acc[2][4] = {};
#pragma unroll
        for (int kk = 0; kk < 4; ++kk) {
            short8 bf[4];
#pragma unroll
            for (int n = 0; n < 4; ++n)
                bf[n] = P[(tj * 8 + cx * 4 + n) * 256 + kk * 64 + l];
#pragma unroll
            for (int m = 0; m < 2; ++m)
#pragma unroll
                for (int n = 0; n < 4; ++n)
                    acc[m][n] = __builtin_amdgcn_mfma_f32_16x16x32_bf16(
                        Af[kk][m], bf[n], acc[m][n], 0, 0, 0);
        }

        // Diagonal tile: poison self elements (row==col). Within this wave,
        // row ry*32+m*16+quad*4+r == col cx*64+n*16+c  iff  diagWave and
        // n == (ry&1)*2+m and c == quad*4+r.
        if (tj == ti && diagWave) {
            const int ns = (ry & 1) * 2;
#pragma unroll
            for (int m = 0; m < 2; ++m)
#pragma unroll
                for (int r = 0; r < 4; ++r) {
                    bool cond = selfQuad && (r == (c & 3));
                    acc[m][ns + m][r] = cond ? SELF_POISON : acc[m][ns + m][r];
                }
        }

        // ---- minimal row-only epilogue: 5 insts per element ----
#pragma unroll
        for (int m = 0; m < 2; ++m) {
#pragma unroll
            for (int n = 0; n < 4; ++n) {
#pragma unroll
                for (int r = 0; r < 4; ++r) {
                    float s2 = acc[m][n][r];
                    RE[m][r] += fast_exp2(s2);
                    RP[m][r] += (li[m][r] == lj[n]) ? s2 : 0.0f;
                }
            }
        }
    }

    // strip end: row reduction across the 16 col-lanes, then PLAIN STORES to
    // this block+wave's private slice. No atomics anywhere in this kernel.
#pragma unroll
    for (int m = 0; m < 2; ++m)
#pragma unroll
        for (int r = 0; r < 4; ++r) {
#pragma unroll
            for (int off = 1; off < 16; off <<= 1) {
                RE[m][r] += __shfl_xor(RE[m][r], off);
                RP[m][r] += __shfl_xor(RP[m][r], off);
            }
        }
    if (c == 0) {
        // undo the diag poison injected into the positive-sums: exactly one
        // -50 per (m,r) in the diag waves of diag-containing blocks.
        if (g == (ti >> 2) && diagWave) {
#pragma unroll
            for (int m = 0; m < 2; ++m)
#pragma unroll
                for (int r = 0; r < 4; ++r) RP[m][r] -= SELF_POISON;
        }
        const int slot = g * 2 + cx;  // 32 private slots per row
#pragma unroll
        for (int m = 0; m < 2; ++m)
#pragma unroll
            for (int r = 0; r < 4; ++r) {
                int gi = i0 + ry * 32 + m * 16 + quad * 4 + r;
                partE[(size_t)gi * 32 + slot] = RE[m][r];
                partP[(size_t)gi * 32 + slot] = RP[m][r];
            }
    }
}

// ---------------- reduce: 128 blocks; one row per 32-lane half-wave ---------
__global__ void reduce_kernel(const float* __restrict__ partE,
                              const float* __restrict__ partP,
                              const int* __restrict__ labels,
                              const int* __restrict__ hist,
                              float* __restrict__ out) {
    __shared__ float ws4[4];
    const int t = threadIdx.x, w = t >> 6, l = t & 63;
    const int half = l >> 5, sl = l & 31;
    const int rbase = blockIdx.x * 64 + w * 16;  // 64 rows/block, 16/wave

    float a = 0.0f;
#pragma unroll
    for (int it = 0; it < 8; ++it) {
        int row = rbase + it * 2 + half;
        float se = partE[(size_t)row * 32 + sl];
        float sp = partP[(size_t)row * 32 + sl];
#pragma unroll
        for (int off = 1; off < 32; off <<= 1) {
            se += __shfl_xor(se, off);
            sp += __shfl_xor(sp, off);
        }
        if (sl == 0) {
            int cnt = hist[labels[row]] - 1;
            if (cnt > 0)
                a += logf(se + 1e-9f) - 0.69314718056f * sp / (float)cnt;
        }
    }
    // wave reduce (only lanes sl==0 carry nonzero a)
#pragma unroll
    for (int off = 1; off < 64; off <<= 1) a += __shfl_xor(a, off);
    if (l == 0) ws4[w] = a;
    __syncthreads();
    if (t == 0) {
        float s = ws4[0] + ws4[1] + ws4[2] + ws4[3];
        atomicAdd(out, s * (1.0f / (float)N));
    }
}

extern "C" void kernel_launch(void* const* d_in, const int* in_sizes, int n_in,
                              void* d_out, int out_size, void* d_ws, size_t ws_size,
                              hipStream_t stream) {
    const float* F      = (const float*)d_in[0];
    const int*   labels = (const int*)d_in[1];
    float* out = (float*)d_out;

    unsigned int* FbP = (unsigned int*)d_ws;                         // 2 MB
    float* partE = (float*)((char*)d_ws + (size_t)2 * 1024 * 1024);  // 1 MB
    float* partP = partE + (size_t)N * 32;                           // 1 MB
    int*   hist  = (int*)(partP + (size_t)N * 32);                   // 4 KB

    zero_kernel<<<1, 1024, 0, stream>>>(hist, out);
    prep_kernel<<<N / 4, 256, 0, stream>>>(F, labels, FbP, hist);
    sim_kernel<<<64 * 16, 512, 0, stream>>>((const short8*)FbP, labels, partE,
                                            partP);
    reduce_kernel<<<128, 256, 0, stream>>>(partE, partP, labels, hist, out);
}

// Round 9
// 238.056 us; speedup vs baseline: 1.8161x; 1.8161x over previous
//
#include <hip/hip_runtime.h>
#include <hip/hip_bf16.h>
#include <math.h>

// SupCon loss, N=8192 D=128 fp32 in, scalar fp32 out.
// Round 12: R11's regression was NOT the 32x64 reshape -- it was the forced
// __launch_bounds__(512,4) capping the unified file at 128 regs/wave, which
// made the allocator spill 1.27 GB of scratch (VGPR=64+spill, sim 368us).
// This round: same reshape (512 threads, 8 waves, 32x64 wave tile -> Af 32,
// acc 32, RE/RP 16, li 8 ~ 125 live regs) with NATURAL register allocation
// (__launch_bounds__(512) only, 256-reg cap). Expected ~3 waves/SIMD vs R10's
// 2. Discriminates: latency-bound (sim 38->~28) vs L2-BW-bound (sim worsens,
// B-fragments now read by 4 waves not 2) vs unknown floor (flat).
// Pipeline: zero -> prep(fragment-major Fb + hist) -> sim (no LDS, no
// barriers, no atomics, private partial stores) -> reduce (128 blocks).

constexpr int N = 8192;
constexpr int D = 128;

typedef __attribute__((ext_vector_type(8))) short short8;  // 8 bf16 = 4 VGPRs
typedef __attribute__((ext_vector_type(4))) float f32x4;

constexpr float SELF_POISON = -50.0f;  // exp2(-50) ~ 9e-16; |s2| <= 14.43 real

__device__ __forceinline__ float fast_exp2(float x) {
#if __has_builtin(__builtin_amdgcn_exp2f)
    return __builtin_amdgcn_exp2f(x);
#else
    return __expf(x * 0.69314718056f);
#endif
}

// ---------------- zero: hist + output accumulator ---------------------------
__global__ void zero_kernel(int* __restrict__ hist, float* __restrict__ out) {
    hist[threadIdx.x] = 0;  // <<<1,1024>>>
    if (threadIdx.x == 0) out[0] = 0.0f;
}

// ---------------- prep: bf16 rows scaled into log2 domain, fragment layout --
// FbP uint index for element pair (row, k=2l): (row>>4)*1024 + (l>>2)*64 +
// (row&15)*4 + (l&3). Chunk chi = l>>2 holds k = 8*chi .. 8*chi+7 in order.
__global__ void prep_kernel(const float* __restrict__ F,
                            const int* __restrict__ labels,
                            unsigned int* __restrict__ FbP,
                            int* __restrict__ hist) {
    int row = blockIdx.x * 4 + (threadIdx.x >> 6);
    int l = threadIdx.x & 63;
    float2 v = ((const float2*)(F + (size_t)row * D))[l];
    float ss = v.x * v.x + v.y * v.y;
#pragma unroll
    for (int off = 32; off > 0; off >>= 1) ss += __shfl_xor(ss, off);
    float sc = sqrtf(14.4269504089f / ss);  // 10 * log2(e), folded
    __hip_bfloat16 hx = __float2bfloat16(v.x * sc);
    __hip_bfloat16 hy = __float2bfloat16(v.y * sc);
    unsigned int ux = *(unsigned short*)&hx;
    unsigned int uy = *(unsigned short*)&hy;
    unsigned int idx = ((unsigned)(row >> 4) << 10) | ((unsigned)(l >> 2) << 6) |
                       ((unsigned)(row & 15) << 2) | (unsigned)(l & 3);
    FbP[idx] = ux | (uy << 16);
    if (l == 0) atomicAdd(&hist[labels[row]], 1);
}

// ---------------- sim: full matrix, MFMA, no LDS/barriers/atomics -----------
// Block (ti,g): 128x128 rows x [4g,4g+3] col-tiles. 512 threads = 8 waves;
// wave w: ry = w>>1 (rows ry*32..+32), cx = w&1 (cols cx*64..+64).
__global__ __launch_bounds__(512) void sim_kernel(
    const short8* __restrict__ P, const int* __restrict__ labels,
    float* __restrict__ partE, float* __restrict__ partP) {
    const int ti = blockIdx.x >> 4;   // 64 row tiles
    const int g  = blockIdx.x & 15;   // 16 column groups
    const int tjs = g * 4;
    const int i0 = ti * 128;

    const int t = threadIdx.x, w = t >> 6, l = t & 63;
    const int c = l & 15, quad = l >> 4;    // MFMA lane split
    const int ry = w >> 1;                  // 0..3: rows ry*32..+32
    const int cx = w & 1;                   // 0..1: cols cx*64..+64

    // A fragments for the strip: 8 x 1KB coalesced loads, 32 VGPR.
    short8 Af[4][2];  // [kk][m], row16 = ry*2 + m
#pragma unroll
    for (int kk = 0; kk < 4; ++kk)
#pragma unroll
        for (int m = 0; m < 2; ++m)
            Af[kk][m] = P[(ti * 8 + ry * 2 + m) * 256 + kk * 64 + l];

    // row labels for this wave's rows (strip-constant)
    int li[2][4];
#pragma unroll
    for (int m = 0; m < 2; ++m)
#pragma unroll
        for (int r = 0; r < 4; ++r)
            li[m][r] = labels[i0 + ry * 32 + m * 16 + quad * 4 + r];

    const bool selfQuad = (quad == (c >> 2));  // lane may hold self elements
    const bool diagWave = (cx == (ry >> 1));   // wave's cols contain its rows

    float RE[2][4] = {}, RP[2][4] = {};  // row partials, carried across strip

#pragma unroll 1
    for (int tj = tjs; tj < tjs + 4; ++tj) {
        const int j0 = tj * 128;
        int lj[4];
#pragma unroll
        for (int n = 0; n < 4; ++n) lj[n] = labels[j0 + cx * 64 + n * 16 + c];

        f32x4 acc[2][4] = {};
#pragma unroll
        for (int kk = 0; kk < 4; ++kk) {
            short8 bf[4];
#pragma unroll
            for (int n = 0; n < 4; ++n)
                bf[n] = P[(tj * 8 + cx * 4 + n) * 256 + kk * 64 + l];
#pragma unroll
            for (int m = 0; m < 2; ++m)
#pragma unroll
                for (int n = 0; n < 4; ++n)
                    acc[m][n] = __builtin_amdgcn_mfma_f32_16x16x32_bf16(
                        Af[kk][m], bf[n], acc[m][n], 0, 0, 0);
        }

        // Diagonal tile: poison self elements (row==col). Within this wave,
        // row ry*32+m*16+quad*4+r == col cx*64+n*16+c  iff  diagWave and
        // n == (ry&1)*2+m and c == quad*4+r.
        if (tj == ti && diagWave) {
            const int ns = (ry & 1) * 2;
#pragma unroll
            for (int m = 0; m < 2; ++m)
#pragma unroll
                for (int r = 0; r < 4; ++r) {
                    bool cond = selfQuad && (r == (c & 3));
                    acc[m][ns + m][r] = cond ? SELF_POISON : acc[m][ns + m][r];
                }
        }

        // ---- minimal row-only epilogue: 5 insts per element ----
#pragma unroll
        for (int m = 0; m < 2; ++m) {
#pragma unroll
            for (int n = 0; n < 4; ++n) {
#pragma unroll
                for (int r = 0; r < 4; ++r) {
                    float s2 = acc[m][n][r];
                    RE[m][r] += fast_exp2(s2);
                    RP[m][r] += (li[m][r] == lj[n]) ? s2 : 0.0f;
                }
            }
        }
    }

    // strip end: row reduction across the 16 col-lanes, then PLAIN STORES to
    // this block+wave's private slice. No atomics anywhere in this kernel.
#pragma unroll
    for (int m = 0; m < 2; ++m)
#pragma unroll
        for (int r = 0; r < 4; ++r) {
#pragma unroll
            for (int off = 1; off < 16; off <<= 1) {
                RE[m][r] += __shfl_xor(RE[m][r], off);
                RP[m][r] += __shfl_xor(RP[m][r], off);
            }
        }
    if (c == 0) {
        // undo the diag poison injected into the positive-sums: exactly one
        // -50 per (m,r) in the diag waves of diag-containing blocks.
        if (g == (ti >> 2) && diagWave) {
#pragma unroll
            for (int m = 0; m < 2; ++m)
#pragma unroll
                for (int r = 0; r < 4; ++r) RP[m][r] -= SELF_POISON;
        }
        const int slot = g * 2 + cx;  // 32 private slots per row
#pragma unroll
        for (int m = 0; m < 2; ++m)
#pragma unroll
            for (int r = 0; r < 4; ++r) {
                int gi = i0 + ry * 32 + m * 16 + quad * 4 + r;
                partE[(size_t)gi * 32 + slot] = RE[m][r];
                partP[(size_t)gi * 32 + slot] = RP[m][r];
            }
    }
}

// ---------------- reduce: 128 blocks; one row per 32-lane half-wave ---------
__global__ void reduce_kernel(const float* __restrict__ partE,
                              const float* __restrict__ partP,
                              const int* __restrict__ labels,
                              const int* __restrict__ hist,
                              float* __restrict__ out) {
    __shared__ float ws4[4];
    const int t = threadIdx.x, w = t >> 6, l = t & 63;
    const int half = l >> 5, sl = l & 31;
    const int rbase = blockIdx.x * 64 + w * 16;  // 64 rows/block, 16/wave

    float a = 0.0f;
#pragma unroll
    for (int it = 0; it < 8; ++it) {
        int row = rbase + it * 2 + half;
        float se = partE[(size_t)row * 32 + sl];
        float sp = partP[(size_t)row * 32 + sl];
#pragma unroll
        for (int off = 1; off < 32; off <<= 1) {
            se += __shfl_xor(se, off);
            sp += __shfl_xor(sp, off);
        }
        if (sl == 0) {
            int cnt = hist[labels[row]] - 1;
            if (cnt > 0)
                a += logf(se + 1e-9f) - 0.69314718056f * sp / (float)cnt;
        }
    }
    // wave reduce (only lanes sl==0 carry nonzero a)
#pragma unroll
    for (int off = 1; off < 64; off <<= 1) a += __shfl_xor(a, off);
    if (l == 0) ws4[w] = a;
    __syncthreads();
    if (t == 0) {
        float s = ws4[0] + ws4[1] + ws4[2] + ws4[3];
        atomicAdd(out, s * (1.0f / (float)N));
    }
}

extern "C" void kernel_launch(void* const* d_in, const int* in_sizes, int n_in,
                              void* d_out, int out_size, void* d_ws, size_t ws_size,
                              hipStream_t stream) {
    const float* F      = (const float*)d_in[0];
    const int*   labels = (const int*)d_in[1];
    float* out = (float*)d_out;

    unsigned int* FbP = (unsigned int*)d_ws;                         // 2 MB
    float* partE = (float*)((char*)d_ws + (size_t)2 * 1024 * 1024);  // 1 MB
    float* partP = partE + (size_t)N * 32;                           // 1 MB
    int*   hist  = (int*)(partP + (size_t)N * 32);                   // 4 KB

    zero_kernel<<<1, 1024, 0, stream>>>(hist, out);
    prep_kernel<<<N / 4, 256, 0, stream>>>(F, labels, FbP, hist);
    sim_kernel<<<64 * 16, 512, 0, stream>>>((const short8*)FbP, labels, partE,
                                            partP);
    reduce_kernel<<<128, 256, 0, stream>>>(partE, partP, labels, hist, out);
}

// Round 10
// 158.209 us; speedup vs baseline: 2.7327x; 1.5047x over previous
//
#include <hip/hip_runtime.h>
#include <hip/hip_bf16.h>
#include <math.h>

// SupCon loss, N=8192 D=128 fp32 in, scalar fp32 out.
// Round 13: combine the two proven wins that were never combined:
// triangular strips (57% of full-matrix work; R2's decode, correct) +
// atomic-free private-slot partials (R9/R10). The 512-thread occupancy
// reshape is abandoned (R11 forced-bounds spilled 1.27GB; R12 natural
// allocation ALSO spilled 127MB at VGPR=84 -- allocator hostile).
// Structure: 256-thread/4-wave blocks (known VGPR=128, no spill), no LDS,
// no barriers, no atomics in sim. Off-diag tiles: row partials (i side)
// + quad-reduced column partials (j side) plain-stored to private slots
// [j][2*ti+wy]. Diag tiles: row-only with SELF_POISON trick (R10).
// Reduce sums row slots [i][2g+wx] (g>=ti>>2) and col slots (idx<2*tji),
// validity computed from row index so unwritten slots are never read.

constexpr int N = 8192;
constexpr int D = 128;

typedef __attribute__((ext_vector_type(8))) short short8;  // 8 bf16 = 4 VGPRs
typedef __attribute__((ext_vector_type(4))) float f32x4;

constexpr float SELF_POISON = -50.0f;  // exp2(-50) ~ 9e-16; |s2| <= 14.43 real

__device__ __forceinline__ float fast_exp2(float x) {
#if __has_builtin(__builtin_amdgcn_exp2f)
    return __builtin_amdgcn_exp2f(x);
#else
    return __expf(x * 0.69314718056f);
#endif
}

// ---------------- zero: hist + output accumulator ---------------------------
__global__ void zero_kernel(int* __restrict__ hist, float* __restrict__ out) {
    hist[threadIdx.x] = 0;  // <<<1,1024>>>
    if (threadIdx.x == 0) out[0] = 0.0f;
}

// ---------------- prep: bf16 rows scaled into log2 domain, fragment layout --
// FbP uint index for element pair (row, k=2l): (row>>4)*1024 + (l>>2)*64 +
// (row&15)*4 + (l&3). Chunk chi = l>>2 holds k = 8*chi .. 8*chi+7 in order.
__global__ void prep_kernel(const float* __restrict__ F,
                            const int* __restrict__ labels,
                            unsigned int* __restrict__ FbP,
                            int* __restrict__ hist) {
    int row = blockIdx.x * 4 + (threadIdx.x >> 6);
    int l = threadIdx.x & 63;
    float2 v = ((const float2*)(F + (size_t)row * D))[l];
    float ss = v.x * v.x + v.y * v.y;
#pragma unroll
    for (int off = 32; off > 0; off >>= 1) ss += __shfl_xor(ss, off);
    float sc = sqrtf(14.4269504089f / ss);  // 10 * log2(e), folded
    __hip_bfloat16 hx = __float2bfloat16(v.x * sc);
    __hip_bfloat16 hy = __float2bfloat16(v.y * sc);
    unsigned int ux = *(unsigned short*)&hx;
    unsigned int uy = *(unsigned short*)&hy;
    unsigned int idx = ((unsigned)(row >> 4) << 10) | ((unsigned)(l >> 2) << 6) |
                       ((unsigned)(row & 15) << 2) | (unsigned)(l & 3);
    FbP[idx] = ux | (uy << 16);
    if (l == 0) atomicAdd(&hist[labels[row]], 1);
}

// ---------------- sim: triangular strips, MFMA, no LDS/barriers/atomics -----
// 544 blocks: strip (ti, g) covers tiles tj in [max(ti,4g), 4g+3], g >= ti>>2.
// Wave (wy,wx) owns the 64x64 quadrant (rows wy*64.., cols wx*64..).
__global__ __launch_bounds__(256, 2) void sim_kernel(
    const short8* __restrict__ P, const int* __restrict__ labels,
    float* __restrict__ partRowE, float* __restrict__ partRowP,
    float* __restrict__ partColE, float* __restrict__ partColP) {
    // decode strip: 544 blocks = sum over q of 4 rows * (16-q) groups
    int bid = blockIdx.x, q = 0, base = 0;
    while (bid >= base + 4 * (16 - q)) { base += 4 * (16 - q); ++q; }
    int rem = bid - base, ng = 16 - q;
    int ti = 4 * q + rem / ng;
    int g = 15 - (rem % ng);        // diag-crossing strip (g==q) scheduled last
    int tjs = max(ti, 4 * g), tje = 4 * g + 3;
    const int i0 = ti * 128;

    const int t = threadIdx.x, w = t >> 6, l = t & 63;
    const int c = l & 15, quad = l >> 4;    // MFMA lane split
    const int wy = w >> 1, wx = w & 1;      // 64x64 quadrant per wave

    // A fragments for the whole strip: 16 x 1KB coalesced loads, 64 VGPR.
    short8 Af[4][4];  // [kk][m]
#pragma unroll
    for (int kk = 0; kk < 4; ++kk)
#pragma unroll
        for (int m = 0; m < 4; ++m)
            Af[kk][m] = P[(ti * 8 + wy * 4 + m) * 256 + kk * 64 + l];

    // row labels for this wave's rows (strip-constant)
    int li[4][4];
#pragma unroll
    for (int m = 0; m < 4; ++m)
#pragma unroll
        for (int r = 0; r < 4; ++r)
            li[m][r] = labels[i0 + wy * 64 + m * 16 + quad * 4 + r];

    const bool selfQuad = (quad == (c >> 2));  // lane may hold self elements

    float RE[4][4] = {}, RP[4][4] = {};  // row partials, carried across strip

#pragma unroll 1
    for (int tj = tjs; tj <= tje; ++tj) {
        const int j0 = tj * 128;
        int lj[4];
#pragma unroll
        for (int n = 0; n < 4; ++n) lj[n] = labels[j0 + wx * 64 + n * 16 + c];

        f32x4 acc[4][4] = {};
#pragma unroll
        for (int kk = 0; kk < 4; ++kk) {
            short8 bf[4];
#pragma unroll
            for (int n = 0; n < 4; ++n)
                bf[n] = P[(tj * 8 + wx * 4 + n) * 256 + kk * 64 + l];
#pragma unroll
            for (int m = 0; m < 4; ++m)
#pragma unroll
                for (int n = 0; n < 4; ++n)
                    acc[m][n] = __builtin_amdgcn_mfma_f32_16x16x32_bf16(
                        Af[kk][m], bf[n], acc[m][n], 0, 0, 0);
        }

        if (tj == ti) {
            // Diagonal tile: full 128x128 square computed; rows fully covered
            // in-tile, so row-only. Poison self elements (exp2(-50)~0; the
            // -50 entering RP is corrected at strip end).
            if (wy == wx) {
#pragma unroll
                for (int m = 0; m < 4; ++m)
#pragma unroll
                    for (int r = 0; r < 4; ++r) {
                        bool cond = selfQuad && (r == (c & 3));
                        acc[m][m][r] = cond ? SELF_POISON : acc[m][m][r];
                    }
            }
#pragma unroll
            for (int m = 0; m < 4; ++m) {
#pragma unroll
                for (int n = 0; n < 4; ++n) {
#pragma unroll
                    for (int r = 0; r < 4; ++r) {
                        float s2 = acc[m][n][r];
                        RE[m][r] += fast_exp2(s2);
                        RP[m][r] += (li[m][r] == lj[n]) ? s2 : 0.0f;
                    }
                }
            }
        } else {
            // Off-diag tile: row partials (i side) + column partials (j side).
            float ce[4] = {}, cp[4] = {};
#pragma unroll
            for (int m = 0; m < 4; ++m) {
#pragma unroll
                for (int n = 0; n < 4; ++n) {
#pragma unroll
                    for (int r = 0; r < 4; ++r) {
                        float s2 = acc[m][n][r];
                        float e = fast_exp2(s2);
                        float p = (li[m][r] == lj[n]) ? s2 : 0.0f;
                        RE[m][r] += e;
                        RP[m][r] += p;
                        ce[n] += e;
                        cp[n] += p;
                    }
                }
            }
            // transpose contribution: reduce down the 4 quads (2 shfl levels),
            // then plain-store to this block+wave's private column slots.
#pragma unroll
            for (int n = 0; n < 4; ++n) {
                ce[n] += __shfl_xor(ce[n], 16);
                ce[n] += __shfl_xor(ce[n], 32);
                cp[n] += __shfl_xor(cp[n], 16);
                cp[n] += __shfl_xor(cp[n], 32);
            }
            if (quad == 0) {
#pragma unroll
                for (int n = 0; n < 4; ++n) {
                    int gj = j0 + wx * 64 + n * 16 + c;
                    partColE[(size_t)gj * 128 + ti * 2 + wy] = ce[n];
                    partColP[(size_t)gj * 128 + ti * 2 + wy] = cp[n];
                }
            }
        }
    }

    // strip end: row reduction across the 16 col-lanes, then plain stores to
    // private row slots [i][2g+wx]. No atomics anywhere in this kernel.
#pragma unroll
    for (int m = 0; m < 4; ++m)
#pragma unroll
        for (int r = 0; r < 4; ++r) {
#pragma unroll
            for (int off = 1; off < 16; off <<= 1) {
                RE[m][r] += __shfl_xor(RE[m][r], off);
                RP[m][r] += __shfl_xor(RP[m][r], off);
            }
        }
    if (c == 0) {
        // undo the diag poison injected into the positive-sums: exactly one
        // -50 per (m,r) in the wy==wx waves of the diag-crossing strip.
        if (g == (ti >> 2) && wy == wx) {
#pragma unroll
            for (int m = 0; m < 4; ++m)
#pragma unroll
                for (int r = 0; r < 4; ++r) RP[m][r] -= SELF_POISON;
        }
        const int slot = g * 2 + wx;  // 32 row slots
#pragma unroll
        for (int m = 0; m < 4; ++m)
#pragma unroll
            for (int r = 0; r < 4; ++r) {
                int gi = i0 + wy * 64 + m * 16 + quad * 4 + r;
                partRowE[(size_t)gi * 32 + slot] = RE[m][r];
                partRowP[(size_t)gi * 32 + slot] = RP[m][r];
            }
    }
}

// ---------------- reduce: 128 blocks; one row per 32-lane half-wave ---------
// Row i (tile tji=i>>7): row slots 2g+wx for g in [tji>>2, 15]; col slots
// idx in [0, 2*tji). Unwritten slots are never read (masked by validity).
__global__ void reduce_kernel(const float* __restrict__ partRowE,
                              const float* __restrict__ partRowP,
                              const float* __restrict__ partColE,
                              const float* __restrict__ partColP,
                              const int* __restrict__ labels,
                              const int* __restrict__ hist,
                              float* __restrict__ out) {
    __shared__ float ws4[4];
    const int t = threadIdx.x, w = t >> 6, l = t & 63;
    const int half = l >> 5, sl = l & 31;
    const int rbase = blockIdx.x * 64 + w * 16;  // 64 rows/block, 16/wave

    float a = 0.0f;
#pragma unroll
    for (int it = 0; it < 8; ++it) {
        int row = rbase + it * 2 + half;
        int tji = row >> 7, qi = tji >> 2;
        float se = 0.0f, sp = 0.0f;
        if (sl >= 2 * qi) {  // row slots (32): valid g >= qi
            se += partRowE[(size_t)row * 32 + sl];
            sp += partRowP[(size_t)row * 32 + sl];
        }
#pragma unroll
        for (int k = 0; k < 4; ++k) {  // col slots (128): valid idx < 2*tji
            int idx = sl + 32 * k;
            if (idx < 2 * tji) {
                se += partColE[(size_t)row * 128 + idx];
                sp += partColP[(size_t)row * 128 + idx];
            }
        }
#pragma unroll
        for (int off = 1; off < 32; off <<= 1) {
            se += __shfl_xor(se, off);
            sp += __shfl_xor(sp, off);
        }
        if (sl == 0) {
            int cnt = hist[labels[row]] - 1;
            if (cnt > 0)
                a += logf(se + 1e-9f) - 0.69314718056f * sp / (float)cnt;
        }
    }
    // wave reduce (only lanes sl==0 carry nonzero a)
#pragma unroll
    for (int off = 1; off < 64; off <<= 1) a += __shfl_xor(a, off);
    if (l == 0) ws4[w] = a;
    __syncthreads();
    if (t == 0) {
        float s = ws4[0] + ws4[1] + ws4[2] + ws4[3];
        atomicAdd(out, s * (1.0f / (float)N));
    }
}

extern "C" void kernel_launch(void* const* d_in, const int* in_sizes, int n_in,
                              void* d_out, int out_size, void* d_ws, size_t ws_size,
                              hipStream_t stream) {
    const float* F      = (const float*)d_in[0];
    const int*   labels = (const int*)d_in[1];
    float* out = (float*)d_out;

    char* p = (char*)d_ws;
    unsigned int* FbP = (unsigned int*)p;            p += (size_t)2 * 1024 * 1024;
    float* partRowE = (float*)p;                     p += (size_t)N * 32 * 4;  // 1 MB
    float* partRowP = (float*)p;                     p += (size_t)N * 32 * 4;  // 1 MB
    float* partColE = (float*)p;                     p += (size_t)N * 128 * 4; // 4 MB
    float* partColP = (float*)p;                     p += (size_t)N * 128 * 4; // 4 MB
    int*   hist = (int*)p;

    zero_kernel<<<1, 1024, 0, stream>>>(hist, out);
    prep_kernel<<<N / 4, 256, 0, stream>>>(F, labels, FbP, hist);
    sim_kernel<<<544, 256, 0, stream>>>((const short8*)FbP, labels, partRowE,
                                        partRowP, partColE, partColP);
    reduce_kernel<<<128, 256, 0, stream>>>(partRowE, partRowP, partColE,
                                           partColP, labels, hist, out);
}

// Round 11
// 97.438 us; speedup vs baseline: 4.4370x; 1.6237x over previous
//
#include <hip/hip_runtime.h>
#include <hip/hip_bf16.h>
#include <math.h>

// SupCon loss, N=8192 D=128 fp32 in, scalar fp32 out.
// Round 14: R13 (triangular + col-slots) spilled (115 MB scratch) -- third
// confirmation that this structure has only ~30 spare registers over R10's
// 192/wave. Revert to R10 exactly (full matrix, 256 thr, no LDS/barriers/
// atomics, private slots) and isolate the last untested lever: ILP.
// R10's kk loop serializes {4 L2 loads -> 16 dependent MFMA}; at 2 waves/SIMD
// the ~220cyc L2 latency is exposed ~4x/tile (all-pipes-idle signature).
// Fix: (a) double-buffer bf: prefetch kk+1 loads before kk's MFMAs;
// (b) cross-tile prefetch: issue next tile's kk=0 loads before the epilogue
// (~640 VALU cycles of cover). +16..48 arch VGPR -> ~208-240/wave, still
// 2 waves/SIMD under launch_bounds(256,2). Everything else R10-verbatim.

constexpr int N = 8192;
constexpr int D = 128;

typedef __attribute__((ext_vector_type(8))) short short8;  // 8 bf16 = 4 VGPRs
typedef __attribute__((ext_vector_type(4))) float f32x4;

constexpr float SELF_POISON = -50.0f;  // exp2(-50) ~ 9e-16; |s2| <= 14.43 real

__device__ __forceinline__ float fast_exp2(float x) {
#if __has_builtin(__builtin_amdgcn_exp2f)
    return __builtin_amdgcn_exp2f(x);
#else
    return __expf(x * 0.69314718056f);
#endif
}

// ---------------- zero: hist + output accumulator ---------------------------
__global__ void zero_kernel(int* __restrict__ hist, float* __restrict__ out) {
    hist[threadIdx.x] = 0;  // <<<1,1024>>>
    if (threadIdx.x == 0) out[0] = 0.0f;
}

// ---------------- prep: bf16 rows scaled into log2 domain, fragment layout --
// FbP uint index for element pair (row, k=2l): (row>>4)*1024 + (l>>2)*64 +
// (row&15)*4 + (l&3). Chunk chi = l>>2 holds k = 8*chi .. 8*chi+7 in order.
__global__ void prep_kernel(const float* __restrict__ F,
                            const int* __restrict__ labels,
                            unsigned int* __restrict__ FbP,
                            int* __restrict__ hist) {
    int row = blockIdx.x * 4 + (threadIdx.x >> 6);
    int l = threadIdx.x & 63;
    float2 v = ((const float2*)(F + (size_t)row * D))[l];
    float ss = v.x * v.x + v.y * v.y;
#pragma unroll
    for (int off = 32; off > 0; off >>= 1) ss += __shfl_xor(ss, off);
    float sc = sqrtf(14.4269504089f / ss);  // 10 * log2(e), folded
    __hip_bfloat16 hx = __float2bfloat16(v.x * sc);
    __hip_bfloat16 hy = __float2bfloat16(v.y * sc);
    unsigned int ux = *(unsigned short*)&hx;
    unsigned int uy = *(unsigned short*)&hy;
    unsigned int idx = ((unsigned)(row >> 4) << 10) | ((unsigned)(l >> 2) << 6) |
                       ((unsigned)(row & 15) << 2) | (unsigned)(l & 3);
    FbP[idx] = ux | (uy << 16);
    if (l == 0) atomicAdd(&hist[labels[row]], 1);
}

// ---------------- sim: full matrix, MFMA, no LDS/barriers/atomics -----------
// Block (ti, g): A-frags for row-tile ti in registers; B-tiles tj in
// [4g, 4g+3] streamed from L2 with a 1-deep software pipeline.
#define LOADB(BUF, TJ, KK)                                          \
    _Pragma("unroll") for (int n_ = 0; n_ < 4; ++n_)                \
        BUF[n_] = P[((TJ) * 8 + wx * 4 + n_) * 256 + (KK) * 64 + l];

#define MFMASTEP(BUF, KK)                                           \
    _Pragma("unroll") for (int m_ = 0; m_ < 4; ++m_)                \
        _Pragma("unroll") for (int n_ = 0; n_ < 4; ++n_)            \
            acc[m_][n_] = __builtin_amdgcn_mfma_f32_16x16x32_bf16(  \
                Af[KK][m_], BUF[n_], acc[m_][n_], 0, 0, 0);

__global__ __launch_bounds__(256, 2) void sim_kernel(
    const short8* __restrict__ P, const int* __restrict__ labels,
    float* __restrict__ partE, float* __restrict__ partP) {
    const int ti = blockIdx.x >> 4;   // 64 row tiles
    const int g  = blockIdx.x & 15;   // 16 column groups
    const int tjs = g * 4;
    const int i0 = ti * 128;

    const int t = threadIdx.x, w = t >> 6, l = t & 63;
    const int c = l & 15, quad = l >> 4;    // MFMA lane split
    const int wy = w >> 1, wx = w & 1;      // 64x64 quadrant per wave

    // A fragments for the whole strip: 16 x 1KB coalesced loads, 64 VGPR.
    short8 Af[4][4];  // [kk][m]
#pragma unroll
    for (int kk = 0; kk < 4; ++kk)
#pragma unroll
        for (int m = 0; m < 4; ++m)
            Af[kk][m] = P[(ti * 8 + wy * 4 + m) * 256 + kk * 64 + l];

    // row labels for this wave's rows (strip-constant)
    int li[4][4];
#pragma unroll
    for (int m = 0; m < 4; ++m)
#pragma unroll
        for (int r = 0; r < 4; ++r)
            li[m][r] = labels[i0 + wy * 64 + m * 16 + quad * 4 + r];

    const bool selfQuad = (quad == (c >> 2));  // lane may hold self elements

    float RE[4][4] = {}, RP[4][4] = {};  // row partials, carried across strip

    short8 bfA[4], bfB[4];   // B-fragment double buffer (static indices only)
    LOADB(bfA, tjs, 0);      // prologue: first tile's kk=0 in flight

#pragma unroll 1
    for (int tj = tjs; tj < tjs + 4; ++tj) {
        const int j0 = tj * 128;
        int lj[4];
#pragma unroll
        for (int n = 0; n < 4; ++n) lj[n] = labels[j0 + wx * 64 + n * 16 + c];

        f32x4 acc[4][4] = {};
        // software pipeline: prefetch kk+1 (or next tile's kk=0) before the
        // MFMAs that consume the current buffer.
        LOADB(bfB, tj, 1);
        MFMASTEP(bfA, 0);
        LOADB(bfA, tj, 2);
        MFMASTEP(bfB, 1);
        LOADB(bfB, tj, 3);
        MFMASTEP(bfA, 2);
        const int tp = (tj < tjs + 3) ? tj + 1 : tjs;  // last prefetch harmless
        LOADB(bfA, tp, 0);
        MFMASTEP(bfB, 3);

        // Diagonal tile: poison self elements so the clean epilogue naturally
        // zeroes them (exp2(-50)~0; the -50 entering RP is corrected at store).
        if (tj == ti && wy == wx) {
#pragma unroll
            for (int m = 0; m < 4; ++m)
#pragma unroll
                for (int r = 0; r < 4; ++r) {
                    bool cond = selfQuad && (r == (c & 3));
                    acc[m][m][r] = cond ? SELF_POISON : acc[m][m][r];
                }
        }

        // ---- minimal row-only epilogue: 5 insts per element ----
        // (also covers the latency of the next-tile kk=0 prefetch above)
#pragma unroll
        for (int m = 0; m < 4; ++m) {
#pragma unroll
            for (int n = 0; n < 4; ++n) {
#pragma unroll
                for (int r = 0; r < 4; ++r) {
                    float s2 = acc[m][n][r];
                    RE[m][r] += fast_exp2(s2);
                    RP[m][r] += (li[m][r] == lj[n]) ? s2 : 0.0f;
                }
            }
        }
    }

    // strip end: row reduction across the 16 col-lanes, then PLAIN STORES to
    // this block+wave's private slice. No atomics anywhere in this kernel.
#pragma unroll
    for (int m = 0; m < 4; ++m)
#pragma unroll
        for (int r = 0; r < 4; ++r) {
#pragma unroll
            for (int off = 1; off < 16; off <<= 1) {
                RE[m][r] += __shfl_xor(RE[m][r], off);
                RP[m][r] += __shfl_xor(RP[m][r], off);
            }
        }
    if (c == 0) {
        // undo the diag poison injected into the positive-sums: exactly one
        // -50 per (m,r) row group in waves wy==wx of diag-containing blocks.
        if (g == (ti >> 2) && wy == wx) {
#pragma unroll
            for (int m = 0; m < 4; ++m)
#pragma unroll
                for (int r = 0; r < 4; ++r) RP[m][r] -= SELF_POISON;
        }
        const int slot = g * 2 + wx;  // 32 private slots per row
#pragma unroll
        for (int m = 0; m < 4; ++m)
#pragma unroll
            for (int r = 0; r < 4; ++r) {
                int gi = i0 + wy * 64 + m * 16 + quad * 4 + r;
                partE[(size_t)gi * 32 + slot] = RE[m][r];
                partP[(size_t)gi * 32 + slot] = RP[m][r];
            }
    }
}

// ---------------- reduce: 128 blocks; one row per 32-lane half-wave ---------
__global__ void reduce_kernel(const float* __restrict__ partE,
                              const float* __restrict__ partP,
                              const int* __restrict__ labels,
                              const int* __restrict__ hist,
                              float* __restrict__ out) {
    __shared__ float ws4[4];
    const int t = threadIdx.x, w = t >> 6, l = t & 63;
    const int half = l >> 5, sl = l & 31;
    const int rbase = blockIdx.x * 64 + w * 16;  // 64 rows/block, 16/wave

    float a = 0.0f;
#pragma unroll
    for (int it = 0; it < 8; ++it) {
        int row = rbase + it * 2 + half;
        float se = partE[(size_t)row * 32 + sl];
        float sp = partP[(size_t)row * 32 + sl];
#pragma unroll
        for (int off = 1; off < 32; off <<= 1) {
            se += __shfl_xor(se, off);
            sp += __shfl_xor(sp, off);
        }
        if (sl == 0) {
            int cnt = hist[labels[row]] - 1;
            if (cnt > 0)
                a += logf(se + 1e-9f) - 0.69314718056f * sp / (float)cnt;
        }
    }
    // wave reduce (only lanes sl==0 carry nonzero a)
#pragma unroll
    for (int off = 1; off < 64; off <<= 1) a += __shfl_xor(a, off);
    if (l == 0) ws4[w] = a;
    __syncthreads();
    if (t == 0) {
        float s = ws4[0] + ws4[1] + ws4[2] + ws4[3];
        atomicAdd(out, s * (1.0f / (float)N));
    }
}

extern "C" void kernel_launch(void* const* d_in, const int* in_sizes, int n_in,
                              void* d_out, int out_size, void* d_ws, size_t ws_size,
                              hipStream_t stream) {
    const float* F      = (const float*)d_in[0];
    const int*   labels = (const int*)d_in[1];
    float* out = (float*)d_out;

    unsigned int* FbP = (unsigned int*)d_ws;                         // 2 MB
    float* partE = (float*)((char*)d_ws + (size_t)2 * 1024 * 1024);  // 1 MB
    float* partP = partE + (size_t)N * 32;                           // 1 MB
    int*   hist  = (int*)(partP + (size_t)N * 32);                   // 4 KB

    zero_kernel<<<1, 1024, 0, stream>>>(hist, out);
    prep_kernel<<<N / 4, 256, 0, stream>>>(F, labels, FbP, hist);
    sim_kernel<<<64 * 16, 256, 0, stream>>>((const short8*)FbP, labels, partE,
                                            partP);
    reduce_kernel<<<128, 256, 0, stream>>>(partE, partP, labels, hist, out);
}